// Round 10
// baseline (1347.186 us; speedup 1.0000x reference)
//
#include <hip/hip_runtime.h>

// ---------------------------------------------------------------------------
// QRNN: fc1 (512->256) -> 4 x [GEMM 256->768 + act + gated scan] -> classifier
// bf16 intermediates (threshold 1.93e-2 is ~20% rel tol; bf16 path ~1e-3).
// GEMMs: MFMA 16x16x32 bf16, 128x128 tile, BK=64, global_load_lds(16B) with
// pre-swizzled source + XOR'd ds_read_b128. Scan: 3-pass chunked parallel
// scan (64 chunks x 32 steps). bf16 stored as ushort, manual RNE conversion.
// ---------------------------------------------------------------------------

using u16   = unsigned short;
using s16x8 = __attribute__((ext_vector_type(8))) short;   // MFMA A/B frag
using f32x4 = __attribute__((ext_vector_type(4))) float;   // MFMA C/D frag

#define AS1(p) ((const __attribute__((address_space(1))) void*)(p))
#define AS3(p) ((__attribute__((address_space(3))) void*)(p))

#define NCH 64   // scan chunks
#define CHL 32   // steps per chunk (2048/64)

__device__ __forceinline__ u16 f2bf(float f) {          // RNE f32 -> bf16
  unsigned u = __float_as_uint(f);
  return (u16)((u + 0x7fff + ((u >> 16) & 1)) >> 16);
}
__device__ __forceinline__ float bf2f(u16 b) {
  return __uint_as_float(((unsigned)b) << 16);
}
__device__ __forceinline__ float sigm_f(float x) {
  return __fdividef(1.f, 1.f + __expf(-x));
}
__device__ __forceinline__ float tanh_f(float x) {
  return __fdividef(2.f, 1.f + __expf(-2.f * x)) - 1.f;
}

// --- convert fp32 weights -> bf16 scratch (fc1_w then qrnn_w) --------------
__global__ __launch_bounds__(256) void conv_w_k(const float* __restrict__ fc1w,
                                                const float* __restrict__ qw,
                                                u16* __restrict__ dst) {
  int i = blockIdx.x * 256 + threadIdx.x;   // grid covers 131072 + 786432
  float v = (i < 131072) ? fc1w[i] : qw[i - 131072];
  dst[i] = f2bf(v);
}

// --- layer GEMM: Y[m][768] = act( A[m][256] @ W[768][256]^T + bias ) -------
// m = s*64 + b (time-major). cols 0-255: tanh (z), 256-511: sigm (f),
// 512-767: sigm (o). grid = (6 n-blocks, 1024 m-blocks), 256 thr.
__global__ __launch_bounds__(256) void layer_gemm_k(
    const u16* __restrict__ A, const u16* __restrict__ W,
    const float* __restrict__ bias, u16* __restrict__ Y) {
  __shared__ char smem[32768];
  char* As = smem;           // [128][64] bf16, 16B chunks XOR-swizzled
  char* Bs = smem + 16384;   // [128][64] bf16
  const int tid = threadIdx.x;
  const int lane = tid & 63;
  const int wv = tid >> 6;
  const int l15 = lane & 15, lhi = lane >> 4;
  const int n0 = blockIdx.x * 128;
  const int m0 = blockIdx.y * 128;
  const int wr = wv >> 1, wc = wv & 1;   // 2x2 wave grid, 64x64 per wave

  f32x4 acc[4][4] = {};

  for (int kt = 0; kt < 256; kt += 64) {
#pragma unroll
    for (int i = 0; i < 4; ++i) {
      int s = i * 256 + tid;            // 16B slot 0..1023
      int r = s >> 3, c = s & 7;        // row, chunk-of-8-bf16
      int gk = kt + ((c ^ (r & 7)) << 3);   // pre-swizzled global source
      __builtin_amdgcn_global_load_lds(AS1(A + (m0 + r) * 256 + gk),
                                       AS3(As + s * 16), 16, 0, 0);
      __builtin_amdgcn_global_load_lds(AS1(W + (n0 + r) * 256 + gk),
                                       AS3(Bs + s * 16), 16, 0, 0);
    }
    asm volatile("s_waitcnt vmcnt(0)" ::: "memory");
    __syncthreads();
#pragma unroll
    for (int ks = 0; ks < 2; ++ks) {
      s16x8 av[4], bv[4];
#pragma unroll
      for (int mi = 0; mi < 4; ++mi) {
        int r = wr * 64 + mi * 16 + l15;
        av[mi] = *(const s16x8*)(As + r * 128 +
                                 (((ks * 4 + lhi) ^ (l15 & 7)) << 4));
      }
#pragma unroll
      for (int ni = 0; ni < 4; ++ni) {
        int r = wc * 64 + ni * 16 + l15;
        bv[ni] = *(const s16x8*)(Bs + r * 128 +
                                 (((ks * 4 + lhi) ^ (l15 & 7)) << 4));
      }
#pragma unroll
      for (int mi = 0; mi < 4; ++mi)
#pragma unroll
        for (int ni = 0; ni < 4; ++ni)
          acc[mi][ni] = __builtin_amdgcn_mfma_f32_16x16x32_bf16(
              av[mi], bv[ni], acc[mi][ni], 0, 0, 0);
    }
    __syncthreads();
  }

#pragma unroll
  for (int ni = 0; ni < 4; ++ni) {
    int col = n0 + wc * 64 + ni * 16 + l15;
    float bval = bias[col];
    bool is_z = (col < 256);   // uniform within a 16-col fragment
#pragma unroll
    for (int mi = 0; mi < 4; ++mi) {
      int row = m0 + wr * 64 + mi * 16 + lhi * 4;
#pragma unroll
      for (int j = 0; j < 4; ++j) {
        float v = acc[mi][ni][j] + bval;
        v = is_z ? tanh_f(v) : sigm_f(v);
        Y[(row + j) * 768 + col] = f2bf(v);
      }
    }
  }
}

// --- fc1 GEMM: H0[(s*64+b)][256] = X[b*2048+s][512] @ W1[256][512]^T + b1 --
// A is fp32 staged in LDS (32B-granule swizzle), converted to bf16 on read.
// grid = (2 n-blocks, 1024 m-blocks).
__global__ __launch_bounds__(256) void fc1_gemm_k(
    const float* __restrict__ X, const u16* __restrict__ W,
    const float* __restrict__ bias, u16* __restrict__ H0) {
  __shared__ char smem[49152];
  char* As = smem;           // [128][64] fp32 = 32KB
  char* Bs = smem + 32768;   // [128][64] bf16 = 16KB
  const int tid = threadIdx.x;
  const int lane = tid & 63;
  const int wv = tid >> 6;
  const int l15 = lane & 15, lhi = lane >> 4;
  const int n0 = blockIdx.x * 128;
  const int m0 = blockIdx.y * 128;
  const int wr = wv >> 1, wc = wv & 1;

  f32x4 acc[4][4] = {};

  for (int kt = 0; kt < 512; kt += 64) {
#pragma unroll
    for (int i = 0; i < 8; ++i) {        // A: 2048 16B slots
      int s = i * 256 + tid;
      int r = s >> 4;                    // 16 slots per 256B row
      int s16 = s & 15;
      int c32 = s16 >> 1, half = s16 & 1;
      int gk = ((c32 ^ (r & 7)) << 3) + half * 4;   // fp32 elem offset
      __builtin_amdgcn_global_load_lds(AS1(X + (m0 + r) * 512 + kt + gk),
                                       AS3(As + s * 16), 16, 0, 0);
    }
#pragma unroll
    for (int i = 0; i < 4; ++i) {        // B: 1024 16B slots (bf16)
      int s = i * 256 + tid;
      int r = s >> 3, c = s & 7;
      int gk = kt + ((c ^ (r & 7)) << 3);
      __builtin_amdgcn_global_load_lds(AS1(W + (n0 + r) * 512 + gk),
                                       AS3(Bs + s * 16), 16, 0, 0);
    }
    asm volatile("s_waitcnt vmcnt(0)" ::: "memory");
    __syncthreads();
#pragma unroll
    for (int ks = 0; ks < 2; ++ks) {
      s16x8 av[4], bv[4];
#pragma unroll
      for (int mi = 0; mi < 4; ++mi) {
        int r = wr * 64 + mi * 16 + l15;
        const float* p = (const float*)(As + r * 256 +
                                        (((ks * 4 + lhi) ^ (l15 & 7)) << 5));
        f32x4 lo = *(const f32x4*)(p);
        f32x4 hi = *(const f32x4*)(p + 4);
        s16x8 t;
        t[0] = (short)f2bf(lo[0]); t[1] = (short)f2bf(lo[1]);
        t[2] = (short)f2bf(lo[2]); t[3] = (short)f2bf(lo[3]);
        t[4] = (short)f2bf(hi[0]); t[5] = (short)f2bf(hi[1]);
        t[6] = (short)f2bf(hi[2]); t[7] = (short)f2bf(hi[3]);
        av[mi] = t;
      }
#pragma unroll
      for (int ni = 0; ni < 4; ++ni) {
        int r = wc * 64 + ni * 16 + l15;
        bv[ni] = *(const s16x8*)(Bs + r * 128 +
                                 (((ks * 4 + lhi) ^ (l15 & 7)) << 4));
      }
#pragma unroll
      for (int mi = 0; mi < 4; ++mi)
#pragma unroll
        for (int ni = 0; ni < 4; ++ni)
          acc[mi][ni] = __builtin_amdgcn_mfma_f32_16x16x32_bf16(
              av[mi], bv[ni], acc[mi][ni], 0, 0, 0);
    }
    __syncthreads();
  }

#pragma unroll
  for (int ni = 0; ni < 4; ++ni) {
    int col = n0 + wc * 64 + ni * 16 + l15;
    float bval = bias[col];
#pragma unroll
    for (int mi = 0; mi < 4; ++mi) {
      int row = m0 + wr * 64 + mi * 16 + lhi * 4;
#pragma unroll
      for (int j = 0; j < 4; ++j) {
        int m = row + j;                 // m = b*2048 + s
        int sidx = m & 2047, b = m >> 11;
        H0[(sidx * 64 + b) * 256 + col] = f2bf(acc[mi][ni][j] + bval);
      }
    }
  }
}

// --- scan pass A: per-chunk affine transform (A = prod f, B = local scan) --
__global__ __launch_bounds__(256) void scan_passA_k(
    const u16* __restrict__ Y, float* __restrict__ Av,
    float* __restrict__ Bv) {
  int b = blockIdx.x, ci = blockIdx.y, h = threadIdx.x;
  float a = 1.f, v = 0.f;
  int base = ((ci * CHL) * 64 + b) * 768 + h;
  for (int t = 0; t < CHL; ++t) {
    float z = bf2f(Y[base]);
    float f = bf2f(Y[base + 256]);
    v = f * v + (1.f - f) * z;
    a *= f;
    base += 64 * 768;
  }
  int idx = (ci * 64 + b) * 256 + h;
  Av[idx] = a;
  Bv[idx] = v;
}

// --- scan pass B: scan the 64 chunk transforms; emit per-chunk c_init + h_n
__global__ __launch_bounds__(256) void scan_passB_k(
    const float* __restrict__ Av, const float* __restrict__ Bv,
    float* __restrict__ Cin, float* __restrict__ hn) {
  int bh = blockIdx.x * 256 + threadIdx.x;
  float c = 0.f;
  for (int ci = 0; ci < NCH; ++ci) {
    Cin[ci * 16384 + bh] = c;
    c = Av[ci * 16384 + bh] * c + Bv[ci * 16384 + bh];
  }
  hn[bh] = c;   // c after last step = cs[-1]
}

// --- scan pass C: replay with correct c_init, emit h = o*c ----------------
template <int LAST>
__global__ __launch_bounds__(256) void scan_passC_k(
    const u16* __restrict__ Y, const float* __restrict__ Cin,
    u16* __restrict__ Hb, float* __restrict__ Hf) {
  int b = blockIdx.x, ci = blockIdx.y, h = threadIdx.x;
  float c = Cin[(ci * 64 + b) * 256 + h];
  int base = ((ci * CHL) * 64 + b) * 768 + h;
  int obase = ((ci * CHL) * 64 + b) * 256 + h;
  for (int t = 0; t < CHL; ++t) {
    float z = bf2f(Y[base]);
    float f = bf2f(Y[base + 256]);
    float o = bf2f(Y[base + 512]);
    c = f * c + (1.f - f) * z;
    float hv = o * c;
    if (LAST) Hf[obase] = hv;
    else      Hb[obase] = f2bf(hv);
    base += 64 * 768;
    obase += 64 * 256;
  }
}

// --- classifier: logits = h[-1] @ fc_w^T + fc_b ; softmax ------------------
__global__ __launch_bounds__(640) void classifier_k(
    const float* __restrict__ Hf, const float* __restrict__ fcw,
    const float* __restrict__ fcb, float* __restrict__ cls) {
  __shared__ float logits[640];
  int tid = threadIdx.x;
  int b = tid / 10, c = tid % 10;
  const float* hrow = Hf + (2047 * 64 + b) * 256;
  const float* wrow = fcw + c * 256;
  float acc = fcb[c];
  for (int k = 0; k < 256; ++k) acc += hrow[k] * wrow[k];
  logits[b * 10 + c] = acc;
  __syncthreads();
  float m = -1e30f;
  for (int i = 0; i < 10; ++i) m = fmaxf(m, logits[b * 10 + i]);
  float s = 0.f;
  for (int i = 0; i < 10; ++i) s += __expf(logits[b * 10 + i] - m);
  cls[b * 10 + c] = __expf(acc - m) / s;
}

extern "C" void kernel_launch(void* const* d_in, const int* in_sizes, int n_in,
                              void* d_out, int out_size, void* d_ws,
                              size_t ws_size, hipStream_t stream) {
  const float* x      = (const float*)d_in[0];
  const float* fc1_w  = (const float*)d_in[1];
  const float* fc1_b  = (const float*)d_in[2];
  const float* qrnn_w = (const float*)d_in[3];
  const float* qrnn_b = (const float*)d_in[4];
  const float* fc_w   = (const float*)d_in[5];
  const float* fc_b   = (const float*)d_in[6];

  float* out     = (float*)d_out;
  float* out_h   = out;                       // (S,B,H) = 33554432 floats
  float* out_cls = out + 33554432;            // (B,10)  = 640
  float* out_hn  = out + 33555072;            // (4,B,H) = 65536

  // workspace layout (bytes): weights-bf16 | Y | Hbuf | A | B | Cin  (~270MB)
  char* ws = (char*)d_ws;
  u16*   Wb  = (u16*)ws;                               // 917504 bf16
  u16*   Y   = (u16*)(ws + 2097152);                   // 192 MB
  u16*   Hb  = (u16*)(ws + 2097152 + 201326592);       // 64 MB
  float* Av  = (float*)(ws + 270532608);               // 4 MB
  float* Bv  = (float*)(ws + 274726912);               // 4 MB
  float* Cin = (float*)(ws + 278921216);               // 4 MB

  conv_w_k<<<3584, 256, 0, stream>>>(fc1_w, qrnn_w, Wb);
  fc1_gemm_k<<<dim3(2, 1024), 256, 0, stream>>>(x, Wb, fc1_b, Hb);
  for (int l = 0; l < 4; ++l) {
    const u16* Wl = Wb + 131072 + l * (768 * 256);
    layer_gemm_k<<<dim3(6, 1024), 256, 0, stream>>>(Hb, Wl, qrnn_b + l * 768, Y);
    scan_passA_k<<<dim3(64, 64), 256, 0, stream>>>(Y, Av, Bv);
    scan_passB_k<<<64, 256, 0, stream>>>(Av, Bv, Cin, out_hn + l * 16384);
    if (l < 3)
      scan_passC_k<0><<<dim3(64, 64), 256, 0, stream>>>(Y, Cin, Hb, nullptr);
    else
      scan_passC_k<1><<<dim3(64, 64), 256, 0, stream>>>(Y, Cin, nullptr, out_h);
  }
  classifier_k<<<1, 640, 0, stream>>>(out_h, fc_w, fc_b, out_cls);
}

// Round 13
// 1240.228 us; speedup vs baseline: 1.0862x; 1.0862x over previous
//
#include <hip/hip_runtime.h>

// ---------------------------------------------------------------------------
// QRNN: fc1 (512->256) -> 4 x [GEMM 256->768 + act + gated scan] -> classifier
// R11 change: LDS-transposed GEMM epilogues -> dwordx4 coalesced C-writes.
// R10 counters showed 1.9x write amplification + write-allocate fetch from
// 32B-segment bf16 stores (layer_gemm 580MB vs 260MB ideal hbm_bytes).
// ---------------------------------------------------------------------------

using u16   = unsigned short;
using s16x8 = __attribute__((ext_vector_type(8))) short;   // MFMA A/B frag
using f32x4 = __attribute__((ext_vector_type(4))) float;   // MFMA C/D frag

#define AS1(p) ((const __attribute__((address_space(1))) void*)(p))
#define AS3(p) ((__attribute__((address_space(3))) void*)(p))

#define NCH 64   // scan chunks
#define CHL 32   // steps per chunk (2048/64)

__device__ __forceinline__ u16 f2bf(float f) {          // RNE f32 -> bf16
  unsigned u = __float_as_uint(f);
  return (u16)((u + 0x7fff + ((u >> 16) & 1)) >> 16);
}
__device__ __forceinline__ float bf2f(u16 b) {
  return __uint_as_float(((unsigned)b) << 16);
}
__device__ __forceinline__ float sigm_f(float x) {
  return __fdividef(1.f, 1.f + __expf(-x));
}
__device__ __forceinline__ float tanh_f(float x) {
  return __fdividef(2.f, 1.f + __expf(-2.f * x)) - 1.f;
}

// --- convert fp32 weights -> bf16 scratch (fc1_w then qrnn_w) --------------
__global__ __launch_bounds__(256) void conv_w_k(const float* __restrict__ fc1w,
                                                const float* __restrict__ qw,
                                                u16* __restrict__ dst) {
  int i = blockIdx.x * 256 + threadIdx.x;   // grid covers 131072 + 786432
  float v = (i < 131072) ? fc1w[i] : qw[i - 131072];
  dst[i] = f2bf(v);
}

// --- layer GEMM: Y[m][768] = act( A[m][256] @ W[768][256]^T + bias ) -------
// m = s*64 + b (time-major). Block covers 128 cols, entirely inside one of
// the z/f/o planes -> activation is block-uniform. Epilogue: LDS transpose
// ([128] rows x 272B stride) then dwordx4 stores (256B/row contiguous).
__global__ __launch_bounds__(256) void layer_gemm_k(
    const u16* __restrict__ A, const u16* __restrict__ W,
    const float* __restrict__ bias, u16* __restrict__ Y) {
  __shared__ char smem[34816];
  char* As = smem;           // [128][64] bf16, 16B chunks XOR-swizzled
  char* Bs = smem + 16384;   // [128][64] bf16
  const int tid = threadIdx.x;
  const int lane = tid & 63;
  const int wv = tid >> 6;
  const int l15 = lane & 15, lhi = lane >> 4;
  const int n0 = blockIdx.x * 128;
  const int m0 = blockIdx.y * 128;
  const int wr = wv >> 1, wc = wv & 1;   // 2x2 wave grid, 64x64 per wave

  f32x4 acc[4][4] = {};

  for (int kt = 0; kt < 256; kt += 64) {
#pragma unroll
    for (int i = 0; i < 4; ++i) {
      int s = i * 256 + tid;            // 16B slot 0..1023
      int r = s >> 3, c = s & 7;        // row, chunk-of-8-bf16
      int gk = kt + ((c ^ (r & 7)) << 3);   // pre-swizzled global source
      __builtin_amdgcn_global_load_lds(AS1(A + (m0 + r) * 256 + gk),
                                       AS3(As + s * 16), 16, 0, 0);
      __builtin_amdgcn_global_load_lds(AS1(W + (n0 + r) * 256 + gk),
                                       AS3(Bs + s * 16), 16, 0, 0);
    }
    asm volatile("s_waitcnt vmcnt(0)" ::: "memory");
    __syncthreads();
#pragma unroll
    for (int ks = 0; ks < 2; ++ks) {
      s16x8 av[4], bv[4];
#pragma unroll
      for (int mi = 0; mi < 4; ++mi) {
        int r = wr * 64 + mi * 16 + l15;
        av[mi] = *(const s16x8*)(As + r * 128 +
                                 (((ks * 4 + lhi) ^ (l15 & 7)) << 4));
      }
#pragma unroll
      for (int ni = 0; ni < 4; ++ni) {
        int r = wc * 64 + ni * 16 + l15;
        bv[ni] = *(const s16x8*)(Bs + r * 128 +
                                 (((ks * 4 + lhi) ^ (l15 & 7)) << 4));
      }
#pragma unroll
      for (int mi = 0; mi < 4; ++mi)
#pragma unroll
        for (int ni = 0; ni < 4; ++ni)
          acc[mi][ni] = __builtin_amdgcn_mfma_f32_16x16x32_bf16(
              av[mi], bv[ni], acc[mi][ni], 0, 0, 0);
    }
    __syncthreads();
  }

  // --- LDS-transposed epilogue (activation applied before pack) ---
  u16* Ct = (u16*)smem;                 // [128][136] u16, 272B row stride
  const bool blk_z = (n0 < 256);        // block-uniform activation
#pragma unroll
  for (int ni = 0; ni < 4; ++ni) {
    int col_t = wc * 64 + ni * 16 + l15;
    float bval = bias[n0 + col_t];
#pragma unroll
    for (int mi = 0; mi < 4; ++mi) {
      int row_t = wr * 64 + mi * 16 + lhi * 4;
#pragma unroll
      for (int j = 0; j < 4; ++j) {
        float v = acc[mi][ni][j] + bval;
        v = blk_z ? tanh_f(v) : sigm_f(v);
        Ct[(row_t + j) * 136 + col_t] = f2bf(v);
      }
    }
  }
  __syncthreads();
#pragma unroll
  for (int i = 0; i < 8; ++i) {
    int slot = i * 256 + tid;           // 2048 16B slots
    int r = slot >> 4, cc = slot & 15;
    uint4 vv = *(const uint4*)((const char*)Ct + r * 272 + cc * 16);
    *(uint4*)(&Y[(m0 + r) * 768 + n0 + cc * 8]) = vv;
  }
}

// --- fc1 GEMM: H0[(s*64+b)][256] = X[b*2048+s][512] @ W1[256][512]^T + b1 --
// A is fp32 staged in LDS (32B-granule swizzle), converted to bf16 on read.
// Same LDS-transposed epilogue. grid = (2 n-blocks, 1024 m-blocks).
__global__ __launch_bounds__(256) void fc1_gemm_k(
    const float* __restrict__ X, const u16* __restrict__ W,
    const float* __restrict__ bias, u16* __restrict__ H0) {
  __shared__ char smem[49152];
  char* As = smem;           // [128][64] fp32 = 32KB
  char* Bs = smem + 32768;   // [128][64] bf16 = 16KB
  const int tid = threadIdx.x;
  const int lane = tid & 63;
  const int wv = tid >> 6;
  const int l15 = lane & 15, lhi = lane >> 4;
  const int n0 = blockIdx.x * 128;
  const int m0 = blockIdx.y * 128;
  const int wr = wv >> 1, wc = wv & 1;

  f32x4 acc[4][4] = {};

  for (int kt = 0; kt < 512; kt += 64) {
#pragma unroll
    for (int i = 0; i < 8; ++i) {        // A: 2048 16B slots
      int s = i * 256 + tid;
      int r = s >> 4;                    // 16 slots per 256B row
      int s16 = s & 15;
      int c32 = s16 >> 1, half = s16 & 1;
      int gk = ((c32 ^ (r & 7)) << 3) + half * 4;   // fp32 elem offset
      __builtin_amdgcn_global_load_lds(AS1(X + (m0 + r) * 512 + kt + gk),
                                       AS3(As + s * 16), 16, 0, 0);
    }
#pragma unroll
    for (int i = 0; i < 4; ++i) {        // B: 1024 16B slots (bf16)
      int s = i * 256 + tid;
      int r = s >> 3, c = s & 7;
      int gk = kt + ((c ^ (r & 7)) << 3);
      __builtin_amdgcn_global_load_lds(AS1(W + (n0 + r) * 512 + gk),
                                       AS3(Bs + s * 16), 16, 0, 0);
    }
    asm volatile("s_waitcnt vmcnt(0)" ::: "memory");
    __syncthreads();
#pragma unroll
    for (int ks = 0; ks < 2; ++ks) {
      s16x8 av[4], bv[4];
#pragma unroll
      for (int mi = 0; mi < 4; ++mi) {
        int r = wr * 64 + mi * 16 + l15;
        const float* p = (const float*)(As + r * 256 +
                                        (((ks * 4 + lhi) ^ (l15 & 7)) << 5));
        f32x4 lo = *(const f32x4*)(p);
        f32x4 hi = *(const f32x4*)(p + 4);
        s16x8 t;
        t[0] = (short)f2bf(lo[0]); t[1] = (short)f2bf(lo[1]);
        t[2] = (short)f2bf(lo[2]); t[3] = (short)f2bf(lo[3]);
        t[4] = (short)f2bf(hi[0]); t[5] = (short)f2bf(hi[1]);
        t[6] = (short)f2bf(hi[2]); t[7] = (short)f2bf(hi[3]);
        av[mi] = t;
      }
#pragma unroll
      for (int ni = 0; ni < 4; ++ni) {
        int r = wc * 64 + ni * 16 + l15;
        bv[ni] = *(const s16x8*)(Bs + r * 128 +
                                 (((ks * 4 + lhi) ^ (l15 & 7)) << 4));
      }
#pragma unroll
      for (int mi = 0; mi < 4; ++mi)
#pragma unroll
        for (int ni = 0; ni < 4; ++ni)
          acc[mi][ni] = __builtin_amdgcn_mfma_f32_16x16x32_bf16(
              av[mi], bv[ni], acc[mi][ni], 0, 0, 0);
    }
    __syncthreads();
  }

  // --- LDS-transposed epilogue ---
  u16* Ct = (u16*)smem;                 // [128][136] u16, 272B row stride
#pragma unroll
  for (int ni = 0; ni < 4; ++ni) {
    int col_t = wc * 64 + ni * 16 + l15;
    float bval = bias[n0 + col_t];
#pragma unroll
    for (int mi = 0; mi < 4; ++mi) {
      int row_t = wr * 64 + mi * 16 + lhi * 4;
#pragma unroll
      for (int j = 0; j < 4; ++j)
        Ct[(row_t + j) * 136 + col_t] = f2bf(acc[mi][ni][j] + bval);
    }
  }
  __syncthreads();
#pragma unroll
  for (int i = 0; i < 8; ++i) {
    int slot = i * 256 + tid;
    int r = slot >> 4, cc = slot & 15;
    uint4 vv = *(const uint4*)((const char*)Ct + r * 272 + cc * 16);
    int m = m0 + r;                     // m = b*2048 + s
    int sidx = m & 2047, b = m >> 11;
    *(uint4*)(&H0[(sidx * 64 + b) * 256 + n0 + cc * 8]) = vv;
  }
}

// --- scan pass A: per-chunk affine transform (A = prod f, B = local scan) --
__global__ __launch_bounds__(256) void scan_passA_k(
    const u16* __restrict__ Y, float* __restrict__ Av,
    float* __restrict__ Bv) {
  int b = blockIdx.x, ci = blockIdx.y, h = threadIdx.x;
  float a = 1.f, v = 0.f;
  int base = ((ci * CHL) * 64 + b) * 768 + h;
  for (int t = 0; t < CHL; ++t) {
    float z = bf2f(Y[base]);
    float f = bf2f(Y[base + 256]);
    v = f * v + (1.f - f) * z;
    a *= f;
    base += 64 * 768;
  }
  int idx = (ci * 64 + b) * 256 + h;
  Av[idx] = a;
  Bv[idx] = v;
}

// --- scan pass B: scan the 64 chunk transforms; emit per-chunk c_init + h_n
__global__ __launch_bounds__(256) void scan_passB_k(
    const float* __restrict__ Av, const float* __restrict__ Bv,
    float* __restrict__ Cin, float* __restrict__ hn) {
  int bh = blockIdx.x * 256 + threadIdx.x;
  float c = 0.f;
  for (int ci = 0; ci < NCH; ++ci) {
    Cin[ci * 16384 + bh] = c;
    c = Av[ci * 16384 + bh] * c + Bv[ci * 16384 + bh];
  }
  hn[bh] = c;   // c after last step = cs[-1]
}

// --- scan pass C: replay with correct c_init, emit h = o*c ----------------
template <int LAST>
__global__ __launch_bounds__(256) void scan_passC_k(
    const u16* __restrict__ Y, const float* __restrict__ Cin,
    u16* __restrict__ Hb, float* __restrict__ Hf) {
  int b = blockIdx.x, ci = blockIdx.y, h = threadIdx.x;
  float c = Cin[(ci * 64 + b) * 256 + h];
  int base = ((ci * CHL) * 64 + b) * 768 + h;
  int obase = ((ci * CHL) * 64 + b) * 256 + h;
  for (int t = 0; t < CHL; ++t) {
    float z = bf2f(Y[base]);
    float f = bf2f(Y[base + 256]);
    float o = bf2f(Y[base + 512]);
    c = f * c + (1.f - f) * z;
    float hv = o * c;
    if (LAST) Hf[obase] = hv;
    else      Hb[obase] = f2bf(hv);
    base += 64 * 768;
    obase += 64 * 256;
  }
}

// --- classifier: logits = h[-1] @ fc_w^T + fc_b ; softmax ------------------
__global__ __launch_bounds__(640) void classifier_k(
    const float* __restrict__ Hf, const float* __restrict__ fcw,
    const float* __restrict__ fcb, float* __restrict__ cls) {
  __shared__ float logits[640];
  int tid = threadIdx.x;
  int b = tid / 10, c = tid % 10;
  const float* hrow = Hf + (2047 * 64 + b) * 256;
  const float* wrow = fcw + c * 256;
  float acc = fcb[c];
  for (int k = 0; k < 256; ++k) acc += hrow[k] * wrow[k];
  logits[b * 10 + c] = acc;
  __syncthreads();
  float m = -1e30f;
  for (int i = 0; i < 10; ++i) m = fmaxf(m, logits[b * 10 + i]);
  float s = 0.f;
  for (int i = 0; i < 10; ++i) s += __expf(logits[b * 10 + i] - m);
  cls[b * 10 + c] = __expf(acc - m) / s;
}

extern "C" void kernel_launch(void* const* d_in, const int* in_sizes, int n_in,
                              void* d_out, int out_size, void* d_ws,
                              size_t ws_size, hipStream_t stream) {
  const float* x      = (const float*)d_in[0];
  const float* fc1_w  = (const float*)d_in[1];
  const float* fc1_b  = (const float*)d_in[2];
  const float* qrnn_w = (const float*)d_in[3];
  const float* qrnn_b = (const float*)d_in[4];
  const float* fc_w   = (const float*)d_in[5];
  const float* fc_b   = (const float*)d_in[6];

  float* out     = (float*)d_out;
  float* out_h   = out;                       // (S,B,H) = 33554432 floats
  float* out_cls = out + 33554432;            // (B,10)  = 640
  float* out_hn  = out + 33555072;            // (4,B,H) = 65536

  // workspace layout (bytes): weights-bf16 | Y | Hbuf | A | B | Cin  (~270MB)
  char* ws = (char*)d_ws;
  u16*   Wb  = (u16*)ws;                               // 917504 bf16
  u16*   Y   = (u16*)(ws + 2097152);                   // 192 MB
  u16*   Hb  = (u16*)(ws + 2097152 + 201326592);       // 64 MB
  float* Av  = (float*)(ws + 270532608);               // 4 MB
  float* Bv  = (float*)(ws + 274726912);               // 4 MB
  float* Cin = (float*)(ws + 278921216);               // 4 MB

  conv_w_k<<<3584, 256, 0, stream>>>(fc1_w, qrnn_w, Wb);
  fc1_gemm_k<<<dim3(2, 1024), 256, 0, stream>>>(x, Wb, fc1_b, Hb);
  for (int l = 0; l < 4; ++l) {
    const u16* Wl = Wb + 131072 + l * (768 * 256);
    layer_gemm_k<<<dim3(6, 1024), 256, 0, stream>>>(Hb, Wl, qrnn_b + l * 768, Y);
    scan_passA_k<<<dim3(64, 64), 256, 0, stream>>>(Y, Av, Bv);
    scan_passB_k<<<64, 256, 0, stream>>>(Av, Bv, Cin, out_hn + l * 16384);
    if (l < 3)
      scan_passC_k<0><<<dim3(64, 64), 256, 0, stream>>>(Y, Cin, Hb, nullptr);
    else
      scan_passC_k<1><<<dim3(64, 64), 256, 0, stream>>>(Y, Cin, nullptr, out_h);
  }
  classifier_k<<<1, 640, 0, stream>>>(out_h, fc_w, fc_b, out_cls);
}